// Round 4
// baseline (100.349 us; speedup 1.0000x reference)
//
#include <hip/hip_runtime.h>
#include <hip/hip_cooperative_groups.h>
#include <float.h>

namespace cg = cooperative_groups;

// ChamferLoss via MFMA, R14: ONE cooperative dispatch, zero extra nodes.
// B=4, N=16384, M=4096, fp32 in/out.
// loss[b] = (1/N) * sum_n min_m max(||p_bn - v_bm||^2, 0)
//
// d2 = pp + (v2 - 2 p.v). Bracket on the MATRIX pipe via split-bf16 in K=16
// of mfma_f32_32x32x16_bf16 (encoding validated R6-R13, absmax 0.0):
//   A row (VERT):   [-2vh x3, -2vh x3, -2vl x3, v2h, v2l, 0...]
//   B col (POINT):  [ph x3, pl x3, ph x3, 1, 1, 0...]
//
// R14: R13 showed per-dispatch overhead ~2.5us and a fixed ~40us harness
// workspace-poison fill. Changes vs R13:
// (1) the memset node is gone -- the kernel is launched cooperatively;
//     blocks write per-block sums (pre-scaled by 1/N, same per-term
//     arithmetic as the old atomicAdd terms) to a 1KB ws slab, grid.sync(),
//     then blocks 0..3 tree-reduce 64 values and STORE out[b] directly.
// (2) chunk-1 tv coords are prefetched into registers during chunk-0's MFMA
//     phase (issue-early/write-late), hiding the L2/HBM latency that was
//     exposed at the chunk boundary.
// Everything else (frag encodings, min-fold order, per-block summation tree)
// is byte-identical to R13.

typedef __bf16 bf16x8 __attribute__((ext_vector_type(8)));
typedef float  f32x16 __attribute__((ext_vector_type(16)));

constexpr int B = 4, N = 16384, M = 4096;
constexpr int BN = B * N;                 // 65536 points total
constexpr int TPB = 512;                  // 8 waves: 4 point-spans x 2 M-halves
constexpr int PPB = 256;                  // points per block
constexpr int NPB = BN / PPB;             // 256 blocks = 1/CU
constexpr int CHUNK = 2048;               // verts per LDS pass (64 KB frags)
constexpr int NCH = M / CHUNK;            // 2 chunks
constexpr int CT = CHUNK / 32;            // 64 tiles per chunk
constexpr int HT = CT / 2;                // 32 tiles per wave per chunk

__global__ __launch_bounds__(TPB) void chamfer_coop(
    const float* __restrict__ src, const float* __restrict__ tv,
    float* __restrict__ bs, float* __restrict__ out)
{
    __shared__ uint4 lds4[4096];                 // 64 KB, reused by epilogue
    char* ldsc = (char*)lds4;

    const int pblk = blockIdx.x;
    const int b    = pblk >> 6;                  // 64 blocks per batch
    const int t    = threadIdx.x;
    const int w    = t >> 6, L = t & 63;
    const int s    = w & 3, h = w >> 2;
    const int half = L >> 5, c = L & 31;
    const int laneoff = half * 512 + c * 16;

    // Two points per lane: group0 = span base + c, group1 = +32.
    const int P0 = pblk * PPB + s * 64;
    const int p0 = P0 + c, p1 = P0 + 32 + c;
    float x0 = src[3 * p0], y0 = src[3 * p0 + 1], z0 = src[3 * p0 + 2];
    float x1 = src[3 * p1], y1 = src[3 * p1 + 1], z1 = src[3 * p1 + 2];
    float pp0 = fmaf(x0, x0, fmaf(y0, y0, z0 * z0));
    float pp1 = fmaf(x1, x1, fmaf(y1, y1, z1 * z1));

    __bf16 one = (__bf16)1.0f, zero = (__bf16)0.0f;
    bf16x8 bP0, bP1;
    {
        __bf16 xh = (__bf16)x0, yh = (__bf16)y0, zh = (__bf16)z0;
        __bf16 xl = (__bf16)(x0 - (float)xh), yl = (__bf16)(y0 - (float)yh),
               zl = (__bf16)(z0 - (float)zh);
        if (half == 0) { bP0[0]=xh; bP0[1]=yh; bP0[2]=zh; bP0[3]=xl; bP0[4]=yl; bP0[5]=zl; bP0[6]=xh; bP0[7]=yh; }
        else { bP0[0]=zh; bP0[1]=one; bP0[2]=one; bP0[3]=zero; bP0[4]=zero; bP0[5]=zero; bP0[6]=zero; bP0[7]=zero; }
    }
    {
        __bf16 xh = (__bf16)x1, yh = (__bf16)y1, zh = (__bf16)z1;
        __bf16 xl = (__bf16)(x1 - (float)xh), yl = (__bf16)(y1 - (float)yh),
               zl = (__bf16)(z1 - (float)zh);
        if (half == 0) { bP1[0]=xh; bP1[1]=yh; bP1[2]=zh; bP1[3]=xl; bP1[4]=yl; bP1[5]=zl; bP1[6]=xh; bP1[7]=yh; }
        else { bP1[0]=zh; bP1[1]=one; bP1[2]=one; bP1[3]=zero; bP1[4]=zero; bP1[5]=zero; bP1[6]=zero; bP1[7]=zero; }
    }

    f32x16 zeroC;
#pragma unroll
    for (int r = 0; r < 16; ++r) zeroC[r] = 0.0f;
    float mn0[8], mn1[8];
#pragma unroll
    for (int u = 0; u < 8; ++u) { mn0[u] = FLT_MAX; mn1[u] = FLT_MAX; }

    // Chunk-0 coords preloaded; chunk-1 coords prefetched during chunk-0 MFMA.
    float cx[4], cy[4], cz[4], nx[4], ny[4], nz[4];
#pragma unroll
    for (int k = 0; k < 4; ++k) {
        int i = b * M + t + k * 512;
        cx[k] = tv[3 * i + 0]; cy[k] = tv[3 * i + 1]; cz[k] = tv[3 * i + 2];
    }

#pragma unroll
    for (int ch = 0; ch < NCH; ++ch) {
        if (ch) __syncthreads();                 // prior chunk's reads done

        // ---- Build this chunk's A-frags (4 verts/thread, stride 512).
        // Same ops as the validated pre-pass -> byte-identical fragments.
#pragma unroll
        for (int k = 0; k < 4; ++k) {
            int ml = t + k * 512;                // vert-in-chunk 0..2047
            float x = cx[k], y = cy[k], z = cz[k];
            __bf16 xh = (__bf16)x, yh = (__bf16)y, zh = (__bf16)z;
            float xhf = (float)xh, yhf = (float)yh, zhf = (float)zh;
            __bf16 xl = (__bf16)(x - xhf), yl = (__bf16)(y - yhf),
                   zl = (__bf16)(z - zhf);
            float v2 = fmaf(x, x, fmaf(y, y, z * z));
            __bf16 v2h = (__bf16)v2;
            __bf16 v2l = (__bf16)(v2 - (float)v2h);

            bf16x8 h0, h1;
            h0[0] = (__bf16)(-2.0f * xhf); h0[1] = (__bf16)(-2.0f * yhf);
            h0[2] = (__bf16)(-2.0f * zhf);
            h0[3] = h0[0]; h0[4] = h0[1]; h0[5] = h0[2];
            h0[6] = (__bf16)(-2.0f * (float)xl); h0[7] = (__bf16)(-2.0f * (float)yl);
            h1[0] = (__bf16)(-2.0f * (float)zl); h1[1] = v2h; h1[2] = v2l;
            h1[3] = zero; h1[4] = zero; h1[5] = zero; h1[6] = zero; h1[7] = zero;

            size_t base = (size_t)(ml >> 5) * 1024 + (size_t)(ml & 31) * 16;
            *(bf16x8*)(ldsc + base)       = h0;
            *(bf16x8*)(ldsc + base + 512) = h1;
        }

        // Prefetch next chunk's coords (issue-early; consumed after MFMA).
        if (ch + 1 < NCH) {
#pragma unroll
            for (int k = 0; k < 4; ++k) {
                int i = b * M + (ch + 1) * CHUNK + t + k * 512;
                nx[k] = tv[3 * i + 0]; ny[k] = tv[3 * i + 1]; nz[k] = tv[3 * i + 2];
            }
        }
        __syncthreads();

        // ---- 32 tiles for this wave's chunk-half: 1 ds_read_b128 + 2 MFMA
        // + 16 v_min3. C-reg r is vert-row (r&3)+8*(r>>2)+4*half of the
        // tile, col = point c -> folding across regs/tiles/chunks is a
        // legal (exact) vert-min.
        const char* abase = ldsc + (size_t)h * (HT * 1024) + laneoff;
#pragma unroll 8
        for (int tt = 0; tt < HT; ++tt) {
            bf16x8 av = *(const bf16x8*)(abase + tt * 1024);
            f32x16 C0 = __builtin_amdgcn_mfma_f32_32x32x16_bf16(av, bP0, zeroC, 0, 0, 0);
            f32x16 C1 = __builtin_amdgcn_mfma_f32_32x32x16_bf16(av, bP1, zeroC, 0, 0, 0);
#pragma unroll
            for (int u = 0; u < 8; ++u) {
                mn0[u] = fminf(fminf(mn0[u], C0[2 * u]), C0[2 * u + 1]);  // v_min3
                mn1[u] = fminf(fminf(mn1[u], C1[2 * u]), C1[2 * u + 1]);
            }
        }

        if (ch + 1 < NCH) {
#pragma unroll
            for (int k = 0; k < 4; ++k) { cx[k] = nx[k]; cy[k] = ny[k]; cz[k] = nz[k]; }
        }
    }

    // ---- Fold 8 accumulators per group; merge lane-halves (L, L+32 share
    // a point, disjoint vert rows); lane L holds point P0+L's full-M-half min.
    float a01 = fminf(fminf(mn0[0], mn0[1]), fminf(mn0[2], mn0[3]));
    float a23 = fminf(fminf(mn0[4], mn0[5]), fminf(mn0[6], mn0[7]));
    float m0 = fminf(a01, a23);
    m0 = fminf(m0, __shfl_xor(m0, 32, 64));
    float b01 = fminf(fminf(mn1[0], mn1[1]), fminf(mn1[2], mn1[3]));
    float b23 = fminf(fminf(mn1[4], mn1[5]), fminf(mn1[6], mn1[7]));
    float m1 = fminf(b01, b23);
    m1 = fminf(m1, __shfl_xor(m1, 32, 64));
    float m  = half ? m1 : m0;
    float pp = half ? pp1 : pp0;

    // ---- Merge the two M-halves (wave w and w+4 hold the same points),
    // then the R12/R13 summation tree verbatim. Reuse the frag LDS.
    __syncthreads();                             // frag reads done; safe to reuse
    float* lf = (float*)ldsc;                    // lf[0..511] = lds_m
    float* acc = lf + 512;                       // lf[512..519] = acc
    lf[t] = m;
    __syncthreads();

    float sum = 0.0f;
    if (w < 4) {
        float mm = fminf(m, lf[t + 256]);
        sum = fmaxf(mm + pp, 0.0f);
    }
    for (int off = 32; off > 0; off >>= 1)
        sum += __shfl_down(sum, off, 64);
    if (L == 0) acc[w] = sum;
    __syncthreads();
    if (t == 0) {
        float ssum = acc[0] + acc[1] + acc[2] + acc[3];
        bs[pblk] = ssum * (1.0f / N);            // same per-term scale as the
    }                                            // old atomicAdd contributions

    // ---- Grid-wide sync, then blocks 0..3 reduce 64 block-sums per batch
    // and STORE out[b] (no memset, no atomics needed).
    cg::this_grid().sync();

    if (pblk < B && w == 0) {
        float v = bs[pblk * 64 + L];
        for (int off = 32; off > 0; off >>= 1)
            v += __shfl_down(v, off, 64);
        if (L == 0) out[pblk] = v;
    }
}

extern "C" void kernel_launch(void* const* d_in, const int* in_sizes, int n_in,
                              void* d_out, int out_size, void* d_ws, size_t ws_size,
                              hipStream_t stream) {
    const float* src = (const float*)d_in[0];    // (B, N, 3) fp32
    const float* tv  = (const float*)d_in[1];    // (B, M, 3) fp32
    float* out = (float*)d_out;                  // (B,) fp32
    float* bs  = (float*)d_ws;                   // 1 KB block-sum slab

    void* args[] = { (void*)&src, (void*)&tv, (void*)&bs, (void*)&out };
    hipLaunchCooperativeKernel((const void*)chamfer_coop,
                               dim3(NPB), dim3(TPB), args, 0, stream);
}

// Round 5
// 68.873 us; speedup vs baseline: 1.4570x; 1.4570x over previous
//
#include <hip/hip_runtime.h>
#include <float.h>

// ChamferLoss via MFMA, R15: R13 structure (memset node + ONE regular
// dispatch) + R14's register prefetch of chunk-1 coords.
// B=4, N=16384, M=4096, fp32 in/out.
// loss[b] = (1/N) * sum_n min_m max(||p_bn - v_bm||^2, 0)
//
// d2 = pp + (v2 - 2 p.v). Bracket on the MATRIX pipe via split-bf16 in K=16
// of mfma_f32_32x32x16_bf16 (encoding validated R6-R14, absmax 0.0):
//   A row (VERT):   [-2vh x3, -2vh x3, -2vl x3, v2h, v2l, 0...]
//   B col (POINT):  [ph x3, pl x3, ph x3, 1, 1, 0...]
//
// R15: R14 proved hipLaunchCooperativeKernel costs ~35us extra on this
// harness (non-graph-optimized dispatch + full-grid co-residency drain) --
// reverted to regular launch + 16-byte memset node (R13 = 66.8us). Kept
// R14's only good piece: chunk-1 tv coords prefetched into registers during
// chunk-0's MFMA phase (issue-early/write-late), hiding the L2 latency that
// R13 exposed at the chunk boundary. Frag encodings, min-fold order, and the
// summation tree are byte-identical to R13 -> absmax 0.0 preserved.
// Kernel floor: MFMA 3.4us (2048 MFMA-cyc/SIMD) co-issued with 4096
// VALU-cyc/SIMD of v_min3 (m114) + ~1us frag build => ~3-5us; the rest of
// dur_us is the harness's 268MB poison fill (~40us) + reset dispatch train.

typedef __bf16 bf16x8 __attribute__((ext_vector_type(8)));
typedef float  f32x16 __attribute__((ext_vector_type(16)));

constexpr int B = 4, N = 16384, M = 4096;
constexpr int BN = B * N;                 // 65536 points total
constexpr int TPB = 512;                  // 8 waves: 4 point-spans x 2 M-halves
constexpr int PPB = 256;                  // points per block
constexpr int NPB = BN / PPB;             // 256 blocks = 1/CU
constexpr int CHUNK = 2048;               // verts per LDS pass (64 KB frags)
constexpr int NCH = M / CHUNK;            // 2 chunks
constexpr int CT = CHUNK / 32;            // 64 tiles per chunk
constexpr int HT = CT / 2;                // 32 tiles per wave per chunk

__global__ __launch_bounds__(TPB) void chamfer_fused(
    const float* __restrict__ src, const float* __restrict__ tv,
    float* __restrict__ out)
{
    __shared__ uint4 lds4[4096];                 // 64 KB, reused by epilogue
    char* ldsc = (char*)lds4;

    const int pblk = blockIdx.x;
    const int b    = pblk >> 6;                  // 64 blocks per batch
    const int t    = threadIdx.x;
    const int w    = t >> 6, L = t & 63;
    const int s    = w & 3, h = w >> 2;
    const int half = L >> 5, c = L & 31;
    const int laneoff = half * 512 + c * 16;

    // Two points per lane: group0 = span base + c, group1 = +32.
    const int P0 = pblk * PPB + s * 64;
    const int p0 = P0 + c, p1 = P0 + 32 + c;
    float x0 = src[3 * p0], y0 = src[3 * p0 + 1], z0 = src[3 * p0 + 2];
    float x1 = src[3 * p1], y1 = src[3 * p1 + 1], z1 = src[3 * p1 + 2];
    float pp0 = fmaf(x0, x0, fmaf(y0, y0, z0 * z0));
    float pp1 = fmaf(x1, x1, fmaf(y1, y1, z1 * z1));

    __bf16 one = (__bf16)1.0f, zero = (__bf16)0.0f;
    bf16x8 bP0, bP1;
    {
        __bf16 xh = (__bf16)x0, yh = (__bf16)y0, zh = (__bf16)z0;
        __bf16 xl = (__bf16)(x0 - (float)xh), yl = (__bf16)(y0 - (float)yh),
               zl = (__bf16)(z0 - (float)zh);
        if (half == 0) { bP0[0]=xh; bP0[1]=yh; bP0[2]=zh; bP0[3]=xl; bP0[4]=yl; bP0[5]=zl; bP0[6]=xh; bP0[7]=yh; }
        else { bP0[0]=zh; bP0[1]=one; bP0[2]=one; bP0[3]=zero; bP0[4]=zero; bP0[5]=zero; bP0[6]=zero; bP0[7]=zero; }
    }
    {
        __bf16 xh = (__bf16)x1, yh = (__bf16)y1, zh = (__bf16)z1;
        __bf16 xl = (__bf16)(x1 - (float)xh), yl = (__bf16)(y1 - (float)yh),
               zl = (__bf16)(z1 - (float)zh);
        if (half == 0) { bP1[0]=xh; bP1[1]=yh; bP1[2]=zh; bP1[3]=xl; bP1[4]=yl; bP1[5]=zl; bP1[6]=xh; bP1[7]=yh; }
        else { bP1[0]=zh; bP1[1]=one; bP1[2]=one; bP1[3]=zero; bP1[4]=zero; bP1[5]=zero; bP1[6]=zero; bP1[7]=zero; }
    }

    f32x16 zeroC;
#pragma unroll
    for (int r = 0; r < 16; ++r) zeroC[r] = 0.0f;
    float mn0[8], mn1[8];
#pragma unroll
    for (int u = 0; u < 8; ++u) { mn0[u] = FLT_MAX; mn1[u] = FLT_MAX; }

    // Chunk-0 coords preloaded; chunk-1 coords prefetched during chunk-0 MFMA.
    float cx[4], cy[4], cz[4], nx[4], ny[4], nz[4];
#pragma unroll
    for (int k = 0; k < 4; ++k) {
        int i = b * M + t + k * 512;
        cx[k] = tv[3 * i + 0]; cy[k] = tv[3 * i + 1]; cz[k] = tv[3 * i + 2];
    }

#pragma unroll
    for (int ch = 0; ch < NCH; ++ch) {
        if (ch) __syncthreads();                 // prior chunk's reads done

        // ---- Build this chunk's A-frags (4 verts/thread, stride 512).
        // Same ops as the validated pre-pass -> byte-identical fragments.
#pragma unroll
        for (int k = 0; k < 4; ++k) {
            int ml = t + k * 512;                // vert-in-chunk 0..2047
            float x = cx[k], y = cy[k], z = cz[k];
            __bf16 xh = (__bf16)x, yh = (__bf16)y, zh = (__bf16)z;
            float xhf = (float)xh, yhf = (float)yh, zhf = (float)zh;
            __bf16 xl = (__bf16)(x - xhf), yl = (__bf16)(y - yhf),
                   zl = (__bf16)(z - zhf);
            float v2 = fmaf(x, x, fmaf(y, y, z * z));
            __bf16 v2h = (__bf16)v2;
            __bf16 v2l = (__bf16)(v2 - (float)v2h);

            bf16x8 h0, h1;
            h0[0] = (__bf16)(-2.0f * xhf); h0[1] = (__bf16)(-2.0f * yhf);
            h0[2] = (__bf16)(-2.0f * zhf);
            h0[3] = h0[0]; h0[4] = h0[1]; h0[5] = h0[2];
            h0[6] = (__bf16)(-2.0f * (float)xl); h0[7] = (__bf16)(-2.0f * (float)yl);
            h1[0] = (__bf16)(-2.0f * (float)zl); h1[1] = v2h; h1[2] = v2l;
            h1[3] = zero; h1[4] = zero; h1[5] = zero; h1[6] = zero; h1[7] = zero;

            size_t base = (size_t)(ml >> 5) * 1024 + (size_t)(ml & 31) * 16;
            *(bf16x8*)(ldsc + base)       = h0;
            *(bf16x8*)(ldsc + base + 512) = h1;
        }

        // Prefetch next chunk's coords (issue-early; consumed after MFMA).
        if (ch + 1 < NCH) {
#pragma unroll
            for (int k = 0; k < 4; ++k) {
                int i = b * M + (ch + 1) * CHUNK + t + k * 512;
                nx[k] = tv[3 * i + 0]; ny[k] = tv[3 * i + 1]; nz[k] = tv[3 * i + 2];
            }
        }
        __syncthreads();

        // ---- 32 tiles for this wave's chunk-half: 1 ds_read_b128 + 2 MFMA
        // + 16 v_min3. C-reg r is vert-row (r&3)+8*(r>>2)+4*half of the
        // tile, col = point c -> folding across regs/tiles/chunks is a
        // legal (exact) vert-min.
        const char* abase = ldsc + (size_t)h * (HT * 1024) + laneoff;
#pragma unroll 8
        for (int tt = 0; tt < HT; ++tt) {
            bf16x8 av = *(const bf16x8*)(abase + tt * 1024);
            f32x16 C0 = __builtin_amdgcn_mfma_f32_32x32x16_bf16(av, bP0, zeroC, 0, 0, 0);
            f32x16 C1 = __builtin_amdgcn_mfma_f32_32x32x16_bf16(av, bP1, zeroC, 0, 0, 0);
#pragma unroll
            for (int u = 0; u < 8; ++u) {
                mn0[u] = fminf(fminf(mn0[u], C0[2 * u]), C0[2 * u + 1]);  // v_min3
                mn1[u] = fminf(fminf(mn1[u], C1[2 * u]), C1[2 * u + 1]);
            }
        }

        if (ch + 1 < NCH) {
#pragma unroll
            for (int k = 0; k < 4; ++k) { cx[k] = nx[k]; cy[k] = ny[k]; cz[k] = nz[k]; }
        }
    }

    // ---- Fold 8 accumulators per group; merge lane-halves (L, L+32 share
    // a point, disjoint vert rows); lane L holds point P0+L's half-M min.
    float a01 = fminf(fminf(mn0[0], mn0[1]), fminf(mn0[2], mn0[3]));
    float a23 = fminf(fminf(mn0[4], mn0[5]), fminf(mn0[6], mn0[7]));
    float m0 = fminf(a01, a23);
    m0 = fminf(m0, __shfl_xor(m0, 32, 64));
    float b01 = fminf(fminf(mn1[0], mn1[1]), fminf(mn1[2], mn1[3]));
    float b23 = fminf(fminf(mn1[4], mn1[5]), fminf(mn1[6], mn1[7]));
    float m1 = fminf(b01, b23);
    m1 = fminf(m1, __shfl_xor(m1, 32, 64));
    float m  = half ? m1 : m0;
    float pp = half ? pp1 : pp0;

    // ---- Merge the two M-halves (wave w and w+4 hold the same points),
    // then the R12/R13 summation tree verbatim. Reuse the frag LDS.
    __syncthreads();                             // frag reads done; safe to reuse
    float* lf = (float*)ldsc;                    // lf[0..511] = lds_m
    float* acc = lf + 512;                       // lf[512..519] = acc
    lf[t] = m;
    __syncthreads();

    float sum = 0.0f;
    if (w < 4) {
        float mm = fminf(m, lf[t + 256]);
        sum = fmaxf(mm + pp, 0.0f);
    }
    for (int off = 32; off > 0; off >>= 1)
        sum += __shfl_down(sum, off, 64);
    if (L == 0) acc[w] = sum;
    __syncthreads();
    if (t == 0) {
        float ssum = acc[0] + acc[1] + acc[2] + acc[3];
        atomicAdd(&out[b], ssum * (1.0f / N));
    }
}

extern "C" void kernel_launch(void* const* d_in, const int* in_sizes, int n_in,
                              void* d_out, int out_size, void* d_ws, size_t ws_size,
                              hipStream_t stream) {
    const float* src = (const float*)d_in[0];    // (B, N, 3) fp32
    const float* tv  = (const float*)d_in[1];    // (B, M, 3) fp32
    float* out = (float*)d_out;                  // (B,) fp32

    hipMemsetAsync(out, 0, out_size, stream);    // graph-capturable memset node
    chamfer_fused<<<NPB, TPB, 0, stream>>>(src, tv, out);
}